// Round 9
// baseline (85.175 us; speedup 1.0000x reference)
//
#include <hip/hip_runtime.h>
#include <stdint.h>

#define NB   64
#define NPIX 1024
#define DIM  768
#define KTOP 4

// ---------------------------------------------------------------------------
// Kernel 1: sim[b,n] = dot(z[b,n,:], q[b,:]) / sqrt(768)
// One wave per row; lane reads float4 (16B) -> fully coalesced.
// fp64 accumulate, single rounding to fp32. (Proven: absmax 0.)
// DIAGNOSTIC THIS ROUND: launched TWICE (idempotent) so the total-time delta
// vs round 8 (55.5 us) measures this dispatch's cost directly — rocprof's
// top-5 listing hides all sub-113us dispatches behind harness fills.
// ---------------------------------------------------------------------------
__global__ __launch_bounds__(256) void sgatt_sim(const float* __restrict__ z,
                                                 const float* __restrict__ q,
                                                 float* __restrict__ sim) {
    const int b    = blockIdx.y;
    const int lane = threadIdx.x & 63;
    const int wave = threadIdx.x >> 6;
    const float4* qv = reinterpret_cast<const float4*>(q + (size_t)b * DIM);
    const float4 q0 = qv[lane], q1 = qv[lane + 64], q2 = qv[lane + 128];
    const float rt = sqrtf((float)DIM);
#pragma unroll
    for (int r = 0; r < 4; ++r) {
        const int row = blockIdx.x * 16 + wave * 4 + r;
        const float4* zv =
            reinterpret_cast<const float4*>(z + (size_t)(b * NPIX + row) * DIM);
        const float4 z0 = zv[lane], z1 = zv[lane + 64], z2 = zv[lane + 128];
        double acc = (double)z0.x * q0.x + (double)z0.y * q0.y +
                     (double)z0.z * q0.z + (double)z0.w * q0.w;
        acc += (double)z1.x * q1.x + (double)z1.y * q1.y +
               (double)z1.z * q1.z + (double)z1.w * q1.w;
        acc += (double)z2.x * q2.x + (double)z2.y * q2.y +
               (double)z2.z * q2.z + (double)z2.w * q2.w;
#pragma unroll
        for (int o = 32; o > 0; o >>= 1) acc += __shfl_xor(acc, o);
        if (lane == 0) sim[b * NPIX + row] = (float)acc / rt;
    }
}

// ---------------------------------------------------------------------------
// Lock-free union-find in LDS with path halving. Roots only decrease; final
// root of each component = its min flat index (the min pixel can never be
// re-parented), independent of race interleaving -> deterministic labels.
// ---------------------------------------------------------------------------
__device__ inline int uf_find(volatile int* p, int x) {
    int px = p[x];
    while (px != x) {
        const int g = p[px];
        if (g != px) p[x] = g;   // path halving (benign race)
        x = g;
        px = p[x];
    }
    return x;
}

__device__ inline void uf_union(volatile int* p, int a, int b) {
    while (true) {
        a = uf_find(p, a);
        b = uf_find(p, b);
        if (a == b) return;
        const int hi = a > b ? a : b;
        const int lo = a ^ b ^ hi;
        const int old = atomicCAS((int*)&p[hi], hi, lo);
        if (old == hi) return;
        a = old; b = lo;
    }
}

// ---------------------------------------------------------------------------
// Kernel 2: 256 threads x 4 px. Normalize -> Otsu (shfl scan) ->
// CC (union-find + path halving) -> top-4 regions + bg.
// Lean LDS (~8.4 KB) via overlays. (Round-8 proven: absmax 0.)
// ---------------------------------------------------------------------------
__global__ __launch_bounds__(256) void sgatt_region(const float* __restrict__ sim,
                                                    float* __restrict__ out) {
    const int b    = blockIdx.x;
    const int t    = threadIdx.x;
    const int lane = t & 63;
    const int wid  = t >> 6;

    __shared__ int   s_bufA[NPIX];        // s_par -> s_ssum(float)
    __shared__ int   s_bufB[NPIX];        // hist+mbits -> s_area
    __shared__ float s_wA[4], s_wB[4];
    __shared__ float s_avv[4];
    __shared__ int   s_avi[4];
    __shared__ unsigned long long s_part[4];
    __shared__ unsigned long long s_win;
    __shared__ float s_smin, s_smax;
    __shared__ int   s_thr;
    __shared__ int   s_top[KTOP];

    // LDS init: hist = bufB[0:256], mbits = bufB[256:288]
    s_bufB[t] = 0;
    if (t < NPIX / 32) s_bufB[256 + t] = 0;
    int* s_hist = s_bufB;
    unsigned int* s_mbits = reinterpret_cast<unsigned int*>(s_bufB + 256);

    // ---- phase 1: load sim (float4), wave min/max -----------------------
    const float4 sv4 =
        reinterpret_cast<const float4*>(sim + (size_t)b * NPIX)[t];
    const float svj[4] = {sv4.x, sv4.y, sv4.z, sv4.w};
    float mn = fminf(fminf(svj[0], svj[1]), fminf(svj[2], svj[3]));
    float mx = fmaxf(fmaxf(svj[0], svj[1]), fmaxf(svj[2], svj[3]));
#pragma unroll
    for (int o = 32; o > 0; o >>= 1) {
        mn = fminf(mn, __shfl_xor(mn, o));
        mx = fmaxf(mx, __shfl_xor(mx, o));
    }
    if (lane == 0) { s_wA[wid] = mn; s_wB[wid] = mx; }
    __syncthreads();        // also covers hist/mbits zero-init
    if (t == 0) {
        float a = s_wA[0], c = s_wB[0];
        for (int w = 1; w < 4; ++w) { a = fminf(a, s_wA[w]); c = fmaxf(c, s_wB[w]); }
        s_smin = a; s_smax = c;
    }
    __syncthreads();

    // ---- phase 2: sal + u8 (exact fp32, no FMA) + histogram ------------
    const float smin = s_smin;
    const float den0 = __fadd_rn(__fsub_rn(s_smax, smin), 1e-6f);
    float salj[4];
    int u8j[4];
#pragma unroll
    for (int j = 0; j < 4; ++j) {
        salj[j] = __fdiv_rn(__fsub_rn(svj[j], smin), den0);
        int u = (int)floorf(__fmul_rn(salj[j], 255.0f));
        u8j[j] = min(max(u, 0), 255);
        atomicAdd(&s_hist[u8j[j]], 1);
    }
    __syncthreads();

    // ---- phase 3: Otsu. cumsums exact in fp32 (multiples of 2^-10,
    //      numerators < 2^24) -> shuffle-scan order == reference cumsum.
    {
        const float p = __fmul_rn((float)s_hist[t], 1.0f / 1024.0f);
        float w0 = p;
        float mu = __fmul_rn(p, (float)t);
#pragma unroll
        for (int o = 1; o < 64; o <<= 1) {
            const float aw = __shfl_up(w0, o);
            const float am = __shfl_up(mu, o);
            if (lane >= o) { w0 = __fadd_rn(w0, aw); mu = __fadd_rn(mu, am); }
        }
        if (lane == 63) { s_wA[wid] = w0; s_wB[wid] = mu; }
        __syncthreads();
        float mut = 0.0f;
        for (int w = 0; w < 4; ++w) mut = __fadd_rn(mut, s_wB[w]);
        for (int w = 0; w < wid; ++w) {
            w0 = __fadd_rn(w0, s_wA[w]);
            mu = __fadd_rn(mu, s_wB[w]);
        }
        const float num = __fsub_rn(__fmul_rn(mut, w0), mu);
        const float dn  = __fadd_rn(__fmul_rn(w0, __fsub_rn(1.0f, w0)), 1e-12f);
        float v  = __fdiv_rn(__fmul_rn(num, num), dn);
        int   idx = t;
#pragma unroll
        for (int o = 32; o > 0; o >>= 1) {
            const float v2 = __shfl_xor(v, o);
            const int   i2 = __shfl_xor(idx, o);
            if (v2 > v || (v2 == v && i2 < idx)) { v = v2; idx = i2; }
        }
        if (lane == 0) { s_avv[wid] = v; s_avi[wid] = idx; }
    }
    __syncthreads();
    if (t == 0) {
        float bv = s_avv[0]; int bi = s_avi[0];
        for (int w = 1; w < 4; ++w)
            if (s_avv[w] > bv || (s_avv[w] == bv && s_avi[w] < bi)) {
                bv = s_avv[w]; bi = s_avi[w];
            }
        s_thr = bi;
    }
    __syncthreads();
    const int thr = s_thr;

    // ---- phase 4: mask bitmap + union-find init (s_par = bufA) ----------
    int* s_par = s_bufA;
    int mj[4];
#pragma unroll
    for (int j = 0; j < 4; ++j) {
        const int px = 4*t + j;
        mj[j] = (u8j[j] > thr) ? 1 : 0;
        s_par[px] = px;
        if (mj[j]) atomicOr(&s_mbits[px >> 5], 1u << (px & 31));
    }
    __syncthreads();

    // ---- phase 5: one-pass CC via union-find ----------------------------
#pragma unroll
    for (int j = 0; j < 4; ++j) {
        if (!mj[j]) continue;
        const int px = 4*t + j;
        const int r = px >> 5, c = px & 31;
#define ONMASK(p) ((s_mbits[(p) >> 5] >> ((p) & 31)) & 1u)
        if (c > 0 && ONMASK(px - 1))  uf_union(s_par, px, px - 1);
        if (r > 0) {
            if (c > 0 && ONMASK(px - 33)) uf_union(s_par, px, px - 33);
            if (ONMASK(px - 32))          uf_union(s_par, px, px - 32);
            if (c < 31 && ONMASK(px - 31)) uf_union(s_par, px, px - 31);
        }
#undef ONMASK
    }
    __syncthreads();

    // ---- phase 6: resolve labels, then overlay area/ssum ----------------
    int labj[4];
#pragma unroll
    for (int j = 0; j < 4; ++j) {
        const int px = 4*t + j;
        labj[j] = mj[j] ? (uf_find(s_par, px) + 1) : 0;
    }
    __syncthreads();   // everyone done with s_par (bufA) & mbits (bufB)

    float* s_ssum = reinterpret_cast<float*>(s_bufA);  // [label-1], 1..1024
    int*   s_area = s_bufB;                            // [label-1]
#pragma unroll
    for (int j = 0; j < 4; ++j) { s_area[4*t + j] = 0; s_ssum[4*t + j] = 0.0f; }
    __syncthreads();
#pragma unroll
    for (int j = 0; j < 4; ++j) {
        if (mj[j]) {
            atomicAdd(&s_area[labj[j] - 1], 1);
            atomicAdd(&s_ssum[labj[j] - 1], salj[j]);
        }
    }
    __syncthreads();

    // ---- phase 7: candidate keys + top-4 ---------------------------------
    // valid <=> area >= 20.48 <=> area >= 21; mean > 0 so float bits are
    // order-preserving; ~L in low word => ties pick lower label (lax.top_k).
    unsigned long long key[4];
#pragma unroll
    for (int j = 0; j < 4; ++j) {
        const int L = 4*t + j + 1;
        const int a = s_area[L - 1];
        key[j] = 0ull;
        if (a >= 21) {
            const float mean = __fdiv_rn(s_ssum[L - 1], (float)a);
            key[j] = ((unsigned long long)__float_as_uint(mean) << 32) |
                     (unsigned long long)(0xFFFFFFFFu - (unsigned)L);
        }
    }
    for (int k = 0; k < KTOP; ++k) {
        unsigned long long v =
            max(max(key[0], key[1]), max(key[2], key[3]));
#pragma unroll
        for (int o = 32; o > 0; o >>= 1) {
            const unsigned long long w = __shfl_xor(v, o);
            if (w > v) v = w;
        }
        if (lane == 0) s_part[wid] = v;
        __syncthreads();
        if (t == 0) {
            unsigned long long bb = s_part[0];
            for (int w2 = 1; w2 < 4; ++w2)
                if (s_part[w2] > bb) bb = s_part[w2];
            s_win = bb;
            s_top[k] = (bb != 0ull)
                           ? (int)(0xFFFFFFFFu - (unsigned)(bb & 0xFFFFFFFFull))
                           : -1;
        }
        __syncthreads();
        const unsigned long long win = s_win;
#pragma unroll
        for (int j = 0; j < 4; ++j)
            if (key[j] == win && win != 0ull) key[j] = 0ull;
    }

    // ---- phase 8: write regions + background (float4 stores) -------------
    float* ob = out + (size_t)b * 5 * NPIX;
    int anyr[4] = {0, 0, 0, 0};
#pragma unroll
    for (int k = 0; k < KTOP; ++k) {
        const int tl = s_top[k];
        float4 o;
        float* op = reinterpret_cast<float*>(&o);
#pragma unroll
        for (int j = 0; j < 4; ++j) {
            const int match = (tl >= 0 && labj[j] == tl) ? 1 : 0;
            anyr[j] |= match;
            op[j] = (float)match;
        }
        reinterpret_cast<float4*>(ob + (size_t)k * NPIX)[t] = o;
    }
    {
        float4 o;
        float* op = reinterpret_cast<float*>(&o);
#pragma unroll
        for (int j = 0; j < 4; ++j) op[j] = anyr[j] ? 0.0f : 1.0f;
        reinterpret_cast<float4*>(ob + (size_t)KTOP * NPIX)[t] = o;
    }
}

// ---------------------------------------------------------------------------
extern "C" void kernel_launch(void* const* d_in, const int* in_sizes, int n_in,
                              void* d_out, int out_size, void* d_ws, size_t ws_size,
                              hipStream_t stream) {
    const float* z = (const float*)d_in[0];
    const float* q = (const float*)d_in[1];
    float* out = (float*)d_out;
    float* sim = (float*)d_ws;  // NB*NPIX floats = 256 KiB

    dim3 g1(NPIX / 16, NB);
    // DIAGNOSTIC: sim launched twice (idempotent, deterministic). The delta
    // vs round 8's 55.5 us == one sim dispatch + one launch overhead.
    sgatt_sim<<<g1, 256, 0, stream>>>(z, q, sim);
    sgatt_sim<<<g1, 256, 0, stream>>>(z, q, sim);
    sgatt_region<<<NB, 256, 0, stream>>>(sim, out);
}

// Round 10
// 56.838 us; speedup vs baseline: 1.4986x; 1.4986x over previous
//
#include <hip/hip_runtime.h>
#include <stdint.h>

#define NB   64
#define NPIX 1024
#define DIM  768
#define KTOP 4

// ---------------------------------------------------------------------------
// Kernel 1: sim[b,n] = dot(z[b,n,:], q[b,:]) / sqrt(768)
// One wave per row; lane reads float4 (16B) -> fully coalesced.
// fp64 accumulate, single rounding to fp32. (Proven: absmax 0.)
// Measured round 9: ~28-30 us incl. launch (~ supply floor: 99 MB HBM + L3).
// ---------------------------------------------------------------------------
__global__ __launch_bounds__(256) void sgatt_sim(const float* __restrict__ z,
                                                 const float* __restrict__ q,
                                                 float* __restrict__ sim) {
    const int b    = blockIdx.y;
    const int lane = threadIdx.x & 63;
    const int wave = threadIdx.x >> 6;
    const float4* qv = reinterpret_cast<const float4*>(q + (size_t)b * DIM);
    const float4 q0 = qv[lane], q1 = qv[lane + 64], q2 = qv[lane + 128];
    const float rt = sqrtf((float)DIM);
#pragma unroll
    for (int r = 0; r < 4; ++r) {
        const int row = blockIdx.x * 16 + wave * 4 + r;
        const float4* zv =
            reinterpret_cast<const float4*>(z + (size_t)(b * NPIX + row) * DIM);
        const float4 z0 = zv[lane], z1 = zv[lane + 64], z2 = zv[lane + 128];
        double acc = (double)z0.x * q0.x + (double)z0.y * q0.y +
                     (double)z0.z * q0.z + (double)z0.w * q0.w;
        acc += (double)z1.x * q1.x + (double)z1.y * q1.y +
               (double)z1.z * q1.z + (double)z1.w * q1.w;
        acc += (double)z2.x * q2.x + (double)z2.y * q2.y +
               (double)z2.z * q2.z + (double)z2.w * q2.w;
#pragma unroll
        for (int o = 32; o > 0; o >>= 1) acc += __shfl_xor(acc, o);
        if (lane == 0) sim[b * NPIX + row] = (float)acc / rt;
    }
}

// ---------------------------------------------------------------------------
// Lock-free union-find in LDS with path halving. Roots only decrease; final
// root of each component = its min flat index, independent of race
// interleaving -> deterministic labels.
// ---------------------------------------------------------------------------
__device__ inline int uf_find(volatile int* p, int x) {
    int px = p[x];
    while (px != x) {
        const int g = p[px];
        if (g != px) p[x] = g;   // path halving (benign race)
        x = g;
        px = p[x];
    }
    return x;
}

__device__ inline void uf_union(volatile int* p, int a, int b) {
    while (true) {
        a = uf_find(p, a);
        b = uf_find(p, b);
        if (a == b) return;
        const int hi = a > b ? a : b;
        const int lo = a ^ b ^ hi;
        const int old = atomicCAS((int*)&p[hi], hi, lo);
        if (old == hi) return;
        a = old; b = lo;
    }
}

// ---------------------------------------------------------------------------
// Kernel 2: 256 threads x 4 px. Latency-tuned vs round 8:
//  - phase 6: 4 uf_find chains advanced in LOCKSTEP (batched LDS loads, ~4x
//    latency hiding on the longest pointer-chase phase)
//  - phase 7: top-4 on wave 0 only, 16 keys/lane in registers, pure shfl
//    (replaces 8 barriers + 4 serial combines; same keys, same tie-break)
//  - phase 4/5: intra-quad W edges become plain parent stores (exclusive
//    ownership) -> ~25% fewer CAS unions, less root contention
// ---------------------------------------------------------------------------
__global__ __launch_bounds__(256) void sgatt_region(const float* __restrict__ sim,
                                                    float* __restrict__ out) {
    const int b    = blockIdx.x;
    const int t    = threadIdx.x;
    const int lane = t & 63;
    const int wid  = t >> 6;

    __shared__ int   s_bufA[NPIX];        // s_par -> s_ssum(float)
    __shared__ int   s_bufB[NPIX];        // hist+mbits -> s_area
    __shared__ float s_wA[4], s_wB[4];
    __shared__ float s_avv[4];
    __shared__ int   s_avi[4];
    __shared__ float s_smin, s_smax;
    __shared__ int   s_thr;
    __shared__ int   s_top[KTOP];

    // LDS init: hist = bufB[0:256], mbits = bufB[256:288]
    s_bufB[t] = 0;
    if (t < NPIX / 32) s_bufB[256 + t] = 0;
    int* s_hist = s_bufB;
    unsigned int* s_mbits = reinterpret_cast<unsigned int*>(s_bufB + 256);

    // ---- phase 1: load sim (float4), wave min/max -----------------------
    const float4 sv4 =
        reinterpret_cast<const float4*>(sim + (size_t)b * NPIX)[t];
    const float svj[4] = {sv4.x, sv4.y, sv4.z, sv4.w};
    float mn = fminf(fminf(svj[0], svj[1]), fminf(svj[2], svj[3]));
    float mx = fmaxf(fmaxf(svj[0], svj[1]), fmaxf(svj[2], svj[3]));
#pragma unroll
    for (int o = 32; o > 0; o >>= 1) {
        mn = fminf(mn, __shfl_xor(mn, o));
        mx = fmaxf(mx, __shfl_xor(mx, o));
    }
    if (lane == 0) { s_wA[wid] = mn; s_wB[wid] = mx; }
    __syncthreads();        // also covers hist/mbits zero-init
    if (t == 0) {
        float a = s_wA[0], c = s_wB[0];
        for (int w = 1; w < 4; ++w) { a = fminf(a, s_wA[w]); c = fmaxf(c, s_wB[w]); }
        s_smin = a; s_smax = c;
    }
    __syncthreads();

    // ---- phase 2: sal + u8 (exact fp32, no FMA) + histogram ------------
    const float smin = s_smin;
    const float den0 = __fadd_rn(__fsub_rn(s_smax, smin), 1e-6f);
    float salj[4];
    int u8j[4];
#pragma unroll
    for (int j = 0; j < 4; ++j) {
        salj[j] = __fdiv_rn(__fsub_rn(svj[j], smin), den0);
        int u = (int)floorf(__fmul_rn(salj[j], 255.0f));
        u8j[j] = min(max(u, 0), 255);
        atomicAdd(&s_hist[u8j[j]], 1);
    }
    __syncthreads();

    // ---- phase 3: Otsu. cumsums exact in fp32 (multiples of 2^-10,
    //      numerators < 2^24) -> shuffle-scan order == reference cumsum.
    {
        const float p = __fmul_rn((float)s_hist[t], 1.0f / 1024.0f);
        float w0 = p;
        float mu = __fmul_rn(p, (float)t);
#pragma unroll
        for (int o = 1; o < 64; o <<= 1) {
            const float aw = __shfl_up(w0, o);
            const float am = __shfl_up(mu, o);
            if (lane >= o) { w0 = __fadd_rn(w0, aw); mu = __fadd_rn(mu, am); }
        }
        if (lane == 63) { s_wA[wid] = w0; s_wB[wid] = mu; }
        __syncthreads();
        float mut = 0.0f;
        for (int w = 0; w < 4; ++w) mut = __fadd_rn(mut, s_wB[w]);
        for (int w = 0; w < wid; ++w) {
            w0 = __fadd_rn(w0, s_wA[w]);
            mu = __fadd_rn(mu, s_wB[w]);
        }
        const float num = __fsub_rn(__fmul_rn(mut, w0), mu);
        const float dn  = __fadd_rn(__fmul_rn(w0, __fsub_rn(1.0f, w0)), 1e-12f);
        float v  = __fdiv_rn(__fmul_rn(num, num), dn);
        int   idx = t;
#pragma unroll
        for (int o = 32; o > 0; o >>= 1) {
            const float v2 = __shfl_xor(v, o);
            const int   i2 = __shfl_xor(idx, o);
            if (v2 > v || (v2 == v && i2 < idx)) { v = v2; idx = i2; }
        }
        if (lane == 0) { s_avv[wid] = v; s_avi[wid] = idx; }
    }
    __syncthreads();
    if (t == 0) {
        float bv = s_avv[0]; int bi = s_avi[0];
        for (int w = 1; w < 4; ++w)
            if (s_avv[w] > bv || (s_avv[w] == bv && s_avi[w] < bi)) {
                bv = s_avv[w]; bi = s_avi[w];
            }
        s_thr = bi;
    }
    __syncthreads();
    const int thr = s_thr;

    // ---- phase 4: mask bitmap + UF init + intra-quad W chains -----------
    // Edges exist only between ON pixels. W edges inside a thread's quad
    // (exclusive ownership) become plain parent stores; forest invariant
    // (parent <= self) holds, so later unions/finds are unaffected.
    int* s_par = s_bufA;
    int mj[4];
#pragma unroll
    for (int j = 0; j < 4; ++j) {
        const int px = 4*t + j;
        mj[j] = (u8j[j] > thr) ? 1 : 0;
        s_par[px] = (j > 0 && mj[j] && mj[j-1]) ? (px - 1) : px;
        if (mj[j]) atomicOr(&s_mbits[px >> 5], 1u << (px & 31));
    }
    __syncthreads();

    // ---- phase 5: cross-boundary edges via union-find -------------------
#pragma unroll
    for (int j = 0; j < 4; ++j) {
        if (!mj[j]) continue;
        const int px = 4*t + j;
        const int r = px >> 5, c = px & 31;
#define ONMASK(p) ((s_mbits[(p) >> 5] >> ((p) & 31)) & 1u)
        if (j == 0 && c > 0 && ONMASK(px - 1)) uf_union(s_par, px, px - 1);
        if (r > 0) {
            if (c > 0 && ONMASK(px - 33)) uf_union(s_par, px, px - 33);
            if (ONMASK(px - 32))          uf_union(s_par, px, px - 32);
            if (c < 31 && ONMASK(px - 31)) uf_union(s_par, px, px - 31);
        }
#undef ONMASK
    }
    __syncthreads();

    // ---- phase 6: resolve 4 roots in lockstep (batched LDS loads) -------
    int labj[4];
    {
        int cur[4], par[4];
#pragma unroll
        for (int j = 0; j < 4; ++j) cur[j] = 4*t + j;
#pragma unroll
        for (int j = 0; j < 4; ++j) par[j] = s_par[cur[j]];
        while (true) {
            bool any = false;
#pragma unroll
            for (int j = 0; j < 4; ++j) any |= (par[j] != cur[j]);
            if (!any) break;
#pragma unroll
            for (int j = 0; j < 4; ++j) cur[j] = par[j];
#pragma unroll
            for (int j = 0; j < 4; ++j) par[j] = s_par[cur[j]];
        }
#pragma unroll
        for (int j = 0; j < 4; ++j) labj[j] = mj[j] ? (cur[j] + 1) : 0;
    }
    __syncthreads();   // everyone done with s_par (bufA) & mbits (bufB)

    // ---- overlay: zero area/ssum, accumulate ----------------------------
    float* s_ssum = reinterpret_cast<float*>(s_bufA);  // [label-1]
    int*   s_area = s_bufB;                            // [label-1]
#pragma unroll
    for (int j = 0; j < 4; ++j) { s_area[4*t + j] = 0; s_ssum[4*t + j] = 0.0f; }
    __syncthreads();
#pragma unroll
    for (int j = 0; j < 4; ++j) {
        if (mj[j]) {
            atomicAdd(&s_area[labj[j] - 1], 1);
            atomicAdd(&s_ssum[labj[j] - 1], salj[j]);
        }
    }
    __syncthreads();

    // ---- phase 7: top-4 on wave 0 only (16 labels/lane, pure shfl) ------
    // valid <=> area >= 20.48 <=> area >= 21; mean > 0 so float bits are
    // order-preserving; ~L in low word => ties pick lower label (lax.top_k).
    if (wid == 0) {
        unsigned long long key[16];
#pragma unroll
        for (int i = 0; i < 16; ++i) {
            const int idx = lane * 16 + i;          // label = idx + 1
            const int a = s_area[idx];
            key[i] = 0ull;
            if (a >= 21) {
                const float mean = __fdiv_rn(s_ssum[idx], (float)a);
                key[i] = ((unsigned long long)__float_as_uint(mean) << 32) |
                         (unsigned long long)(0xFFFFFFFFu - (unsigned)(idx + 1));
            }
        }
        for (int k = 0; k < KTOP; ++k) {
            unsigned long long v = key[0];
#pragma unroll
            for (int i = 1; i < 16; ++i) v = (key[i] > v) ? key[i] : v;
#pragma unroll
            for (int o = 32; o > 0; o >>= 1) {
                const unsigned long long w = __shfl_xor(v, o);
                if (w > v) v = w;
            }
            if (lane == 0)
                s_top[k] = (v != 0ull)
                               ? (int)(0xFFFFFFFFu - (unsigned)(v & 0xFFFFFFFFull))
                               : -1;
#pragma unroll
            for (int i = 0; i < 16; ++i)
                if (key[i] == v && v != 0ull) key[i] = 0ull;
        }
    }
    __syncthreads();

    // ---- phase 8: write regions + background (float4 stores) -------------
    float* ob = out + (size_t)b * 5 * NPIX;
    int anyr[4] = {0, 0, 0, 0};
#pragma unroll
    for (int k = 0; k < KTOP; ++k) {
        const int tl = s_top[k];
        float4 o;
        float* op = reinterpret_cast<float*>(&o);
#pragma unroll
        for (int j = 0; j < 4; ++j) {
            const int match = (tl >= 0 && labj[j] == tl) ? 1 : 0;
            anyr[j] |= match;
            op[j] = (float)match;
        }
        reinterpret_cast<float4*>(ob + (size_t)k * NPIX)[t] = o;
    }
    {
        float4 o;
        float* op = reinterpret_cast<float*>(&o);
#pragma unroll
        for (int j = 0; j < 4; ++j) op[j] = anyr[j] ? 0.0f : 1.0f;
        reinterpret_cast<float4*>(ob + (size_t)KTOP * NPIX)[t] = o;
    }
}

// ---------------------------------------------------------------------------
extern "C" void kernel_launch(void* const* d_in, const int* in_sizes, int n_in,
                              void* d_out, int out_size, void* d_ws, size_t ws_size,
                              hipStream_t stream) {
    const float* z = (const float*)d_in[0];
    const float* q = (const float*)d_in[1];
    float* out = (float*)d_out;
    float* sim = (float*)d_ws;  // NB*NPIX floats = 256 KiB

    dim3 g1(NPIX / 16, NB);
    sgatt_sim<<<g1, 256, 0, stream>>>(z, q, sim);
    sgatt_region<<<NB, 256, 0, stream>>>(sim, out);
}